// Round 8
// baseline (425.478 us; speedup 1.0000x reference)
//
#include <hip/hip_runtime.h>
#include <hip/hip_bf16.h>

// ---- problem constants ----
#define B_SZ 4
#define S_SZ 2048
#define DM   1024
#define NH   8
#define DK   128
#define DC   32
#define DHR  32
#define T_TOK (B_SZ * S_SZ) // 8192
#define SCALE 0.07905694150420949f // 1/sqrt(160)

typedef unsigned int uint;
typedef unsigned short ushort;
typedef __attribute__((ext_vector_type(8))) short short8;
typedef __attribute__((ext_vector_type(4))) float floatx4;

__device__ __forceinline__ ushort f2bf(float f) {
    uint u = __float_as_uint(f);
    uint r = u + 0x7fffu + ((u >> 16) & 1u);
    return (ushort)(r >> 16);
}
__device__ __forceinline__ uint packbf(float x, float y) {
    return (uint)f2bf(x) | ((uint)f2bf(y) << 16);
}

// async global->LDS, 16B per lane; lds dest = wave-uniform base + lane*16
__device__ __forceinline__ void glds16(const ushort* g, ushort* l) {
    __builtin_amdgcn_global_load_lds(
        (const __attribute__((address_space(1))) uint*)g,
        (__attribute__((address_space(3))) uint*)l, 16, 0, 0);
}

// ============================================================
// Kernel 1: latents. c_q fp32 [T,32]; kcat bf16 [T,64] = [c_kv+b | k_r+b].
// Block: 256 thr / 32 tokens. Grid: T/32 = 256.
// ============================================================
__global__ __launch_bounds__(256) void latent_kernel(
    const float* __restrict__ h_t,
    const float* __restrict__ W_DQ, const float* __restrict__ b_DQ,
    const float* __restrict__ W_DKV, const float* __restrict__ b_DKV,
    const float* __restrict__ W_KR, const float* __restrict__ b_KR,
    float* __restrict__ c_q, ushort* __restrict__ kcat)
{
    __shared__ __align__(16) float hs[32 * 33];
    __shared__ __align__(16) float wq[32 * 32];
    __shared__ __align__(16) float wkv[32 * 32];
    __shared__ __align__(16) float wkr[32 * 32];

    const int tid = threadIdx.x;
    const int t0 = blockIdx.x * 32;
    const int t = tid & 31;
    const int g = tid >> 5;

    float acc_q[4] = {0.f, 0.f, 0.f, 0.f};
    float acc_kv[4] = {0.f, 0.f, 0.f, 0.f};
    float acc_kr[4] = {0.f, 0.f, 0.f, 0.f};

    const int lr = tid >> 3;
    const int lc = (tid & 7) * 4;

    for (int k0 = 0; k0 < DM; k0 += 32) {
        __syncthreads();
        {
            float4 v = *(const float4*)&h_t[(size_t)(t0 + lr) * DM + k0 + lc];
            hs[lr * 33 + lc + 0] = v.x;
            hs[lr * 33 + lc + 1] = v.y;
            hs[lr * 33 + lc + 2] = v.z;
            hs[lr * 33 + lc + 3] = v.w;
        }
        {
            float4 a = *(const float4*)&W_DQ[(size_t)(k0 + lr) * 32 + lc];
            wq[lr * 32 + lc + 0] = a.x; wq[lr * 32 + lc + 1] = a.y;
            wq[lr * 32 + lc + 2] = a.z; wq[lr * 32 + lc + 3] = a.w;
            float4 b = *(const float4*)&W_DKV[(size_t)(k0 + lr) * 32 + lc];
            wkv[lr * 32 + lc + 0] = b.x; wkv[lr * 32 + lc + 1] = b.y;
            wkv[lr * 32 + lc + 2] = b.z; wkv[lr * 32 + lc + 3] = b.w;
            float4 c = *(const float4*)&W_KR[(size_t)(k0 + lr) * 32 + lc];
            wkr[lr * 32 + lc + 0] = c.x; wkr[lr * 32 + lc + 1] = c.y;
            wkr[lr * 32 + lc + 2] = c.z; wkr[lr * 32 + lc + 3] = c.w;
        }
        __syncthreads();
        #pragma unroll 8
        for (int kk = 0; kk < 32; ++kk) {
            float a = hs[t * 33 + kk];
            #pragma unroll
            for (int cc = 0; cc < 4; ++cc) {
                int c = g * 4 + cc;
                acc_q[cc] += a * wq[kk * 32 + c];
                acc_kv[cc] += a * wkv[kk * 32 + c];
                acc_kr[cc] += a * wkr[kk * 32 + c];
            }
        }
    }
    #pragma unroll
    for (int cc = 0; cc < 4; ++cc) {
        int c = g * 4 + cc;
        c_q[(t0 + t) * 32 + c] = acc_q[cc] + b_DQ[c];
        kcat[(size_t)(t0 + t) * 64 + c]      = f2bf(acc_kv[cc] + b_DKV[c]);
        kcat[(size_t)(t0 + t) * 64 + 32 + c] = f2bf(acc_kr[cc] + b_KR[c]);
    }
}

// ============================================================
// Kernel 2a: per-head absorbed q-side matrix.
// Aq[h][i][j] (fp32): j<32: sum_d W_UQ[i,h128+d]*W_UK[j,h128+d]
//                     j>=32: W_QR[i, h*32+(j-32)]
// bq[h][j]: j<32: sum_d b_UQ[h128+d]*W_UK[j,h128+d] ; j>=32: b_QR[h*32+j-32]
// (q-row-constant bias terms cancel in softmax.) Grid: 8.
// ============================================================
__global__ __launch_bounds__(256) void prep_aq_kernel(
    const float* __restrict__ W_UQ, const float* __restrict__ b_UQ,
    const float* __restrict__ W_UK,
    const float* __restrict__ W_QR, const float* __restrict__ b_QR,
    float* __restrict__ Aq, float* __restrict__ bq)
{
    __shared__ float uq[32 * 128];
    __shared__ float uk[32 * 128];
    const int tid = threadIdx.x;
    const int h = blockIdx.x;

    for (int idx = tid; idx < 4096; idx += 256) {
        int i = idx >> 7, d = idx & 127;
        uq[idx] = W_UQ[(size_t)i * 1024 + h * 128 + d];
        uk[idx] = W_UK[(size_t)i * 1024 + h * 128 + d];
    }
    __syncthreads();

    for (int oidx = tid; oidx < 2048; oidx += 256) {
        int i = oidx >> 6, j = oidx & 63;
        float v;
        if (j < 32) {
            v = 0.f;
            for (int d = 0; d < 128; ++d) v += uq[i * 128 + d] * uk[j * 128 + d];
        } else {
            v = W_QR[(size_t)i * 256 + h * 32 + (j - 32)];
        }
        Aq[((size_t)h * 32 + i) * 64 + j] = v;
    }
    if (tid < 64) {
        int j = tid;
        float v;
        if (j < 32) {
            v = 0.f;
            for (int d = 0; d < 128; ++d) v += b_UQ[h * 128 + d] * uk[j * 128 + d];
        } else {
            v = b_QR[h * 32 + (j - 32)];
        }
        bq[h * 64 + j] = v;
    }
}

// ============================================================
// Kernel 2b: absorbed output-side matrix.
// wcT[n][h*32+i] (bf16) = sum_d W_UV[i,h128+d]*W_O[h128+d,n]
// b2[n] = b_O[n] + sum_{h,d} b_UV[h128+d]*W_O[h128+d,n]
// Grid: 64 blocks x 16 n.
// ============================================================
__global__ __launch_bounds__(256) void prep_wc_kernel(
    const float* __restrict__ W_UV, const float* __restrict__ b_UV,
    const float* __restrict__ W_O, const float* __restrict__ b_O,
    ushort* __restrict__ wcT, float* __restrict__ b2)
{
    __shared__ float uv[32 * 128];
    __shared__ float wo[128 * 17];
    const int tid = threadIdx.x;
    const int n0 = blockIdx.x * 16;

    float b2p = 0.f;
    for (int h = 0; h < NH; ++h) {
        __syncthreads();
        for (int idx = tid; idx < 4096; idx += 256) {
            int i = idx >> 7, d = idx & 127;
            uv[idx] = W_UV[(size_t)i * 1024 + h * 128 + d];
        }
        for (int idx = tid; idx < 2048; idx += 256) {
            int d = idx >> 4, j = idx & 15;
            wo[d * 17 + j] = W_O[(size_t)(h * 128 + d) * 1024 + n0 + j];
        }
        __syncthreads();
        for (int oidx = tid; oidx < 512; oidx += 256) {
            int i = oidx & 31, j = oidx >> 5;
            float v = 0.f;
            for (int d = 0; d < 128; ++d) v += uv[i * 128 + d] * wo[d * 17 + j];
            wcT[(size_t)(n0 + j) * 256 + h * 32 + i] = f2bf(v);
        }
        if (tid < 16) {
            int j = tid;
            for (int d = 0; d < 128; ++d) b2p += b_UV[h * 128 + d] * wo[d * 17 + j];
        }
    }
    if (tid < 16) b2[n0 + tid] = b_O[n0 + tid] + b2p;
}

// ============================================================
// Kernel 3: q-tilde. qt[bh][s][64] bf16 = c_q[s] @ Aq_h + bq_h.
// Block 256 thr / 32 tokens, loops 8 heads. Grid: T/32 = 256.
// ============================================================
__global__ __launch_bounds__(256) void qt_kernel(
    const float* __restrict__ c_q, const float* __restrict__ Aq,
    const float* __restrict__ bq, ushort* __restrict__ qt)
{
    __shared__ __align__(16) float cqs[32 * 33];
    __shared__ __align__(16) float aqs[32 * 64];
    __shared__ float bqs[64];
    const int tid = threadIdx.x;
    const int t0 = blockIdx.x * 32;

    for (int idx = tid; idx < 1024; idx += 256) {
        int tok = idx >> 5, i = idx & 31;
        cqs[tok * 33 + i] = c_q[(size_t)(t0 + tok) * 32 + i];
    }

    const int tok = tid >> 3;
    const int jg = (tid & 7) * 8;
    const int tokg = t0 + tok;
    const int b = tokg >> 11, s = tokg & 2047;

    for (int h = 0; h < NH; ++h) {
        __syncthreads();
        for (int idx = tid; idx < 2048; idx += 256) aqs[idx] = Aq[(size_t)h * 2048 + idx];
        if (tid < 64) bqs[tid] = bq[h * 64 + tid];
        __syncthreads();

        float acc[8];
        #pragma unroll
        for (int jj = 0; jj < 8; ++jj) acc[jj] = bqs[jg + jj];
        for (int i = 0; i < 32; ++i) {
            float cv = cqs[tok * 33 + i];
            #pragma unroll
            for (int jj = 0; jj < 8; ++jj) acc[jj] += cv * aqs[i * 64 + jg + jj];
        }
        uint4 v;
        v.x = packbf(acc[0], acc[1]); v.y = packbf(acc[2], acc[3]);
        v.z = packbf(acc[4], acc[5]); v.w = packbf(acc[6], acc[7]);
        *(uint4*)(qt + (((size_t)(b * NH + h) * S_SZ + s) * 64 + jg)) = v;
    }
}

// ============================================================
// Kernel 4: absorbed-MLA flash attention (D=64 scores, D=32 PV).
// 512 thr, 8 waves x 16 Q rows. Sc^T = k~ . q~^T ; U^T = c_kv^T . P^T.
// Key permutation in Ks staging makes P^T a pure register repack
// (identical scheme to rounds 6/7). u = U/l written to ucat [T,256].
// LDS 13824 B. Grid: (S/128, B*H) = (16, 32).
// ============================================================
__global__ __launch_bounds__(512, 4) void attn_mfma_kernel(
    const ushort* __restrict__ qt, const ushort* __restrict__ kcat,
    ushort* __restrict__ ucat)
{
    __shared__ __align__(16) ushort SH[64 * 72 + 32 * 72]; // Ks + Ct
    ushort* const Ks = SH;            // [score-slot][64 d], stride 72
    ushort* const Ct = SH + 64 * 72;  // [32 d][64 keys phys], stride 72

    const int tid = threadIdx.x;
    const int wave = tid >> 6;
    const int lane = tid & 63;
    const int quad = lane >> 4;
    const int l16 = lane & 15;

    const int bh = blockIdx.y;
    const int b = bh >> 3, h = bh & 7;
    const int s0 = blockIdx.x * 128;
    const int qrow_base = s0 + wave * 16;

    // q~ fragments (B-operand): 64 dims -> 2 kb
    short8 qf[2];
    #pragma unroll
    for (int kb = 0; kb < 2; ++kb)
        qf[kb] = *(const short8*)(qt + (((size_t)bh * S_SZ + qrow_base + l16) * 64
                                        + kb * 32 + quad * 8));

    floatx4 oa[2]; // U^T: col(l16)=qrow, row(quad*4+r)=d (vt*16+)
    oa[0] = (floatx4){0.f, 0.f, 0.f, 0.f};
    oa[1] = (floatx4){0.f, 0.f, 0.f, 0.f};
    float m_run = -3.0e38f, l_run = 0.f;

    const uint4* kgbase = (const uint4*)(kcat + (size_t)b * S_SZ * 64);
    const uint* kc32 = (const uint*)(kcat + (size_t)b * S_SZ * 64);
    uint* const Ct32 = (uint*)Ct;

    for (int kt = 0; kt < S_SZ / 64; ++kt) {
        const int k0 = kt * 64;
        __syncthreads(); // prior tile reads done

        // ---- stage k~ tile with score-slot permutation (512 uint4)
        {
            int row = tid >> 3, seg = tid & 7;
            int prow = ((row & 2) >> 1) * 32 + ((row >> 2) & 3) * 8
                     + ((row >> 4) << 1) + (row & 1);
            *(uint4*)&Ks[row * 72 + seg * 8] = kgbase[(size_t)(k0 + prow) * 8 + seg];
        }
        // ---- stage c_kv^T (physical key order), 256 threads
        if (tid < 256) {
            int dp = tid & 15, kpg = tid >> 4; // dp: d-pair, kpg: 2 key-pairs
            #pragma unroll
            for (int c = 0; c < 2; ++c) {
                int kp = kpg * 2 + c; // keys 2kp, 2kp+1
                uint a  = kc32[(size_t)(k0 + 2 * kp) * 32 + dp];
                uint bb = kc32[(size_t)(k0 + 2 * kp + 1) * 32 + dp];
                Ct32[(2 * dp) * 36 + kp]     = (a & 0xffffu) | (bb << 16);
                Ct32[(2 * dp + 1) * 36 + kp] = (a >> 16) | (bb & 0xffff0000u);
            }
        }
        __syncthreads();

        // ---- Sc^T = k~ . q~^T
        floatx4 sc[4];
        #pragma unroll
        for (int ct = 0; ct < 4; ++ct) {
            sc[ct] = (floatx4){0.f, 0.f, 0.f, 0.f};
            #pragma unroll
            for (int kb = 0; kb < 2; ++kb) {
                short8 kf = *(const short8*)&Ks[(ct * 16 + l16) * 72 + kb * 32 + quad * 8];
                sc[ct] = __builtin_amdgcn_mfma_f32_16x16x32_bf16(kf, qf[kb], sc[ct], 0, 0, 0);
            }
        }

        // ---- online softmax (per-lane scalar)
        union PF { short8 s; uint u[4]; };
        PF pf[2];
        {
            float tmax = -3.0e38f;
            #pragma unroll
            for (int ct = 0; ct < 4; ++ct)
                #pragma unroll
                for (int r = 0; r < 4; ++r) {
                    sc[ct][r] *= SCALE;
                    tmax = fmaxf(tmax, sc[ct][r]);
                }
            tmax = fmaxf(tmax, __shfl_xor(tmax, 16));
            tmax = fmaxf(tmax, __shfl_xor(tmax, 32));

            float mnew = fmaxf(m_run, tmax);
            float al = __expf(m_run - mnew);
            m_run = mnew;

            float rsum = 0.f;
            #pragma unroll
            for (int ct = 0; ct < 4; ++ct)
                #pragma unroll
                for (int r = 0; r < 4; ++r) {
                    float p = __expf(sc[ct][r] - mnew);
                    sc[ct][r] = p;
                    rsum += p;
                }
            rsum += __shfl_xor(rsum, 16);
            rsum += __shfl_xor(rsum, 32);
            l_run = l_run * al + rsum;

            #pragma unroll
            for (int vt = 0; vt < 2; ++vt)
                #pragma unroll
                for (int r = 0; r < 4; ++r)
                    oa[vt][r] *= al;

            #pragma unroll
            for (int kb2 = 0; kb2 < 2; ++kb2)
                #pragma unroll
                for (int j2 = 0; j2 < 4; ++j2)
                    pf[kb2].u[j2] = packbf(sc[j2][2 * kb2], sc[j2][2 * kb2 + 1]);
        }

        // ---- U^T += c_kv^T . P^T
        #pragma unroll
        for (int kb2 = 0; kb2 < 2; ++kb2)
            #pragma unroll
            for (int vt = 0; vt < 2; ++vt) {
                short8 vf = *(const short8*)&Ct[(vt * 16 + l16) * 72 + kb2 * 32 + quad * 8];
                oa[vt] = __builtin_amdgcn_mfma_f32_16x16x32_bf16(vf, pf[kb2].s, oa[vt], 0, 0, 0);
            }
    }

    // ---- epilogue: transpose U^T -> u rows via reused LDS, store ucat
    __syncthreads();
    uint* ot32 = (uint*)(SH + wave * (16 * 40)); // 16 rows x 40 us (20 dw)
    {
        float inv = 1.0f / l_run;
        #pragma unroll
        for (int vt = 0; vt < 2; ++vt)
            #pragma unroll
            for (int rp = 0; rp < 2; ++rp)
                ot32[l16 * 20 + vt * 8 + quad * 2 + rp] =
                    packbf(oa[vt][2 * rp] * inv, oa[vt][2 * rp + 1] * inv);
    }
    // same-wave LDS ordering: no barrier needed
    {
        int r_ = lane >> 2, seg = lane & 3;
        uint4 v = *(const uint4*)&ot32[r_ * 20 + seg * 4];
        size_t tok = (size_t)b * S_SZ + qrow_base + r_;
        *(uint4*)(ucat + tok * 256 + h * 32 + seg * 8) = v;
    }
}

// ============================================================
// Kernel 5: out = ucat [8192,256](bf16) @ wcT^T + b2 (fp32 out).
// m97-style 128x128 tile, BK=32, K=256 (8 iters). Grid: (8, 64).
// ============================================================
__global__ __launch_bounds__(256) void final_gemm_kernel(
    const ushort* __restrict__ A,    // ucat [8192][256]
    const ushort* __restrict__ BT,   // wcT  [1024 n][256 k]
    const float* __restrict__ b2, float* __restrict__ out)
{
    __shared__ __align__(16) ushort As[128 * 32];
    __shared__ __align__(16) ushort Bs[128 * 32];

    const int tid = threadIdx.x;
    const int wave = tid >> 6;
    const int lane = tid & 63;
    const int quad = lane >> 4;
    const int l16 = lane & 15;
    const int wr = wave >> 1, wc = wave & 1;

    const int n0 = blockIdx.x * 128;
    const int m0 = blockIdx.y * 128;

    const int lrow = lane >> 2;
    const int lseg = (lane & 3) * 8;

    floatx4 acc[4][4];
    #pragma unroll
    for (int mt = 0; mt < 4; ++mt)
        #pragma unroll
        for (int nt = 0; nt < 4; ++nt)
            acc[mt][nt] = (floatx4){0.f, 0.f, 0.f, 0.f};

    for (int k0 = 0; k0 < 256; k0 += 32) {
        __syncthreads();
        {
            const ushort* g0 = A + (size_t)(m0 + wave * 32 + lrow) * 256 + k0 + lseg;
            glds16(g0, &As[(wave * 32) * 32]);
            const ushort* g1 = A + (size_t)(m0 + wave * 32 + 16 + lrow) * 256 + k0 + lseg;
            glds16(g1, &As[(wave * 32 + 16) * 32]);
        }
        {
            const ushort* g0 = BT + (size_t)(n0 + wave * 32 + lrow) * 256 + k0 + lseg;
            glds16(g0, &Bs[(wave * 32) * 32]);
            const ushort* g1 = BT + (size_t)(n0 + wave * 32 + 16 + lrow) * 256 + k0 + lseg;
            glds16(g1, &Bs[(wave * 32 + 16) * 32]);
        }
        __syncthreads();

        short8 af[4], bf[4];
        #pragma unroll
        for (int mt = 0; mt < 4; ++mt)
            af[mt] = *(const short8*)&As[(wr * 64 + mt * 16 + l16) * 32 + quad * 8];
        #pragma unroll
        for (int nt = 0; nt < 4; ++nt)
            bf[nt] = *(const short8*)&Bs[(wc * 64 + nt * 16 + l16) * 32 + quad * 8];
        #pragma unroll
        for (int mt = 0; mt < 4; ++mt)
            #pragma unroll
            for (int nt = 0; nt < 4; ++nt)
                acc[mt][nt] = __builtin_amdgcn_mfma_f32_16x16x32_bf16(af[mt], bf[nt], acc[mt][nt], 0, 0, 0);
    }

    float bo[4];
    #pragma unroll
    for (int nt = 0; nt < 4; ++nt) bo[nt] = b2[n0 + wc * 64 + nt * 16 + l16];

    #pragma unroll
    for (int mt = 0; mt < 4; ++mt) {
        #pragma unroll
        for (int r = 0; r < 4; ++r) {
            int row = m0 + wr * 64 + mt * 16 + quad * 4 + r;
            float* orow = out + (size_t)row * DM + n0 + wc * 64;
            #pragma unroll
            for (int nt = 0; nt < 4; ++nt)
                orow[nt * 16 + l16] = acc[mt][nt][r] + bo[nt];
        }
    }
}

// ============================================================
extern "C" void kernel_launch(void* const* d_in, const int* in_sizes, int n_in,
                              void* d_out, int out_size, void* d_ws, size_t ws_size,
                              hipStream_t stream) {
    (void)in_sizes; (void)n_in; (void)out_size; (void)ws_size;

    const float* h_t   = (const float*)d_in[0];
    const float* W_DQ  = (const float*)d_in[1];
    const float* b_DQ  = (const float*)d_in[2];
    const float* W_UQ  = (const float*)d_in[3];
    const float* b_UQ  = (const float*)d_in[4];
    const float* W_DKV = (const float*)d_in[5];
    const float* b_DKV = (const float*)d_in[6];
    const float* W_UK  = (const float*)d_in[7];
    const float* b_UK  = (const float*)d_in[8];  // cancels in softmax (row-const)
    const float* W_UV  = (const float*)d_in[9];
    const float* b_UV  = (const float*)d_in[10];
    const float* W_QR  = (const float*)d_in[11];
    const float* b_QR  = (const float*)d_in[12];
    const float* W_KR  = (const float*)d_in[13];
    const float* b_KR  = (const float*)d_in[14];
    const float* W_O   = (const float*)d_in[15];
    const float* b_O   = (const float*)d_in[16];
    (void)b_UK;

    // workspace carve (~15.2 MB)
    float*  c_q  = (float*)d_ws;                          // 8192*32 fp32
    ushort* kcat = (ushort*)(c_q + (size_t)T_TOK * DC);   // 8192*64 bf16
    float*  Aq   = (float*)(kcat + (size_t)T_TOK * 64);   // 8*32*64 fp32
    float*  bq   = Aq + 8 * 32 * 64;                      // 512 fp32
    float*  b2   = bq + 512;                              // 1024 fp32
    ushort* wcT  = (ushort*)(b2 + 1024);                  // 1024*256 bf16
    ushort* qt   = wcT + (size_t)1024 * 256;              // 32*2048*64 bf16
    ushort* ucat = qt + (size_t)B_SZ * NH * S_SZ * 64;    // 8192*256 bf16

    float* out = (float*)d_out;

    prep_aq_kernel<<<NH, 256, 0, stream>>>(W_UQ, b_UQ, W_UK, W_QR, b_QR, Aq, bq);
    prep_wc_kernel<<<64, 256, 0, stream>>>(W_UV, b_UV, W_O, b_O, wcT, b2);

    latent_kernel<<<T_TOK / 32, 256, 0, stream>>>(
        h_t, W_DQ, b_DQ, W_DKV, b_DKV, W_KR, b_KR, c_q, kcat);

    qt_kernel<<<T_TOK / 32, 256, 0, stream>>>(c_q, Aq, bq, qt);

    attn_mfma_kernel<<<dim3(S_SZ / 128, B_SZ * NH), 512, 0, stream>>>(qt, kcat, ucat);

    final_gemm_kernel<<<dim3(DM / 128, T_TOK / 128), 256, 0, stream>>>(
        ucat, wcT, b2, out);
}